// Round 7
// baseline (348.631 us; speedup 1.0000x reference)
//
#include <hip/hip_runtime.h>
#include <cstdint>

// ===================== GCN encoder on MI355X =====================
// out = gcn(relu(gcn(x, W1, b1)), W2, b2)
// gcn(x,W,b)[i] = dinv[i] * ( sum_{e: dst=i} (xW*dinv)[src] + (xW*dinv)[i] ) + b
// dinv = rsqrt(indeg+1) (self-loop), identical for both layers.
//
// R7: bscatter rebuilt as a radix-partition step — block-local counting sort
// in LDS, then COALESCED run writes (R6 post-mortem: 3.2M scattered 4-B
// stores were transaction-bound, ~90 us hidden). Aggregate batches 16 edge
// indices per group for 2x gather MLP. Rest unchanged from R6.

#define BSHIFT 7          // 128 nodes per bucket
#define NBMAX 784         // >= ceil(100000/128) = 782
#define CH 4096           // edges per block in passes A/C
#define MAXB 6016         // LDS-cached bucket capacity (avg 4096, +30 sigma)

typedef __attribute__((ext_vector_type(8))) short bf16x8;
typedef __attribute__((ext_vector_type(4))) float f32x4;

// ---------------- bf16 helpers ----------------
__device__ inline unsigned short f2bf(float f) {
    unsigned u = __float_as_uint(f);
    unsigned r = (u + 0x7FFFu + ((u >> 16) & 1u)) >> 16;  // RNE
    return (unsigned short)r;
}
__device__ inline unsigned pack2(float a, float b) {
    return (unsigned)f2bf(a) | ((unsigned)f2bf(b) << 16);
}
__device__ inline float blo(unsigned u) { return __uint_as_float(u << 16); }
__device__ inline float bhi(unsigned u) { return __uint_as_float(u & 0xFFFF0000u); }

// ---------------- pass A: bucket histogram (+ folded weight prep) ----------
__global__ __launch_bounds__(256) void hist_kernel(const int* __restrict__ dst,
                                                   int* __restrict__ histmat,
                                                   int E, int nb, int nblk,
                                                   const float* __restrict__ W1,
                                                   const float* __restrict__ W2,
                                                   unsigned short* __restrict__ W1t,
                                                   unsigned short* __restrict__ W2t) {
    if (blockIdx.x >= (unsigned)nblk) {
        int i = (blockIdx.x - nblk) * 256 + threadIdx.x;
        if (i < 128 * 64) {
            int k = i >> 6, n = i & 63;
            W1t[n * 128 + k] = f2bf(W1[i]);
        }
        int j = i - 128 * 64;
        if (j >= 0 && j < 64 * 64) {
            int k = j >> 6, n = j & 63;
            W2t[n * 64 + k] = f2bf(W2[j]);
        }
        return;
    }
    __shared__ int hist[NBMAX];
    int t = threadIdx.x;
    for (int b = t; b < nb; b += 256) hist[b] = 0;
    __syncthreads();
    int base = blockIdx.x * CH;
#pragma unroll
    for (int j = 0; j < CH / 1024; ++j) {
        int idx = base + j * 1024 + t * 4;
        if (idx + 4 <= E) {
            int4 d = *(const int4*)(dst + idx);
            atomicAdd(&hist[d.x >> BSHIFT], 1);
            atomicAdd(&hist[d.y >> BSHIFT], 1);
            atomicAdd(&hist[d.z >> BSHIFT], 1);
            atomicAdd(&hist[d.w >> BSHIFT], 1);
        } else {
            for (int k = 0; k < 4; ++k)
                if (idx + k < E) atomicAdd(&hist[dst[idx + k] >> BSHIFT], 1);
        }
    }
    __syncthreads();
    for (int b = t; b < nb; b += 256) histmat[blockIdx.x * nb + b] = hist[b];
}

// ---------------- pass B1: per-bucket scan over blocks ----------------
__global__ __launch_bounds__(256) void scancol_kernel(const int* __restrict__ histmat,
                                                      int* __restrict__ colbase,
                                                      int* __restrict__ buckettotal,
                                                      int nb, int nblk) {
    __shared__ int ts[256];
    int b = blockIdx.x;
    int t = threadIdx.x;
    int v[4];
    int tsum = 0;
#pragma unroll
    for (int k = 0; k < 4; ++k) {
        int blk = t * 4 + k;
        v[k] = (blk < nblk) ? histmat[blk * nb + b] : 0;
        tsum += v[k];
    }
    ts[t] = tsum;
    __syncthreads();
    for (int ofs = 1; ofs < 256; ofs <<= 1) {
        int val = (t >= ofs) ? ts[t - ofs] : 0;
        __syncthreads();
        ts[t] += val;
        __syncthreads();
    }
    int run = ts[t] - tsum;
#pragma unroll
    for (int k = 0; k < 4; ++k) {
        int blk = t * 4 + k;
        if (blk < nblk) colbase[blk * nb + b] = run;
        run += v[k];
    }
    if (t == 255) buckettotal[b] = ts[255];
}

// ---------------- pass B2: scan bucket totals (single block) ----------------
__global__ __launch_bounds__(256) void scanbucket_kernel(const int* __restrict__ buckettotal,
                                                         int* __restrict__ bucketbase,
                                                         int nb, int E) {
    __shared__ int ts[256];
    int t = threadIdx.x;
    int v[4];
    int tsum = 0;
#pragma unroll
    for (int k = 0; k < 4; ++k) {
        int b = t * 4 + k;
        v[k] = (b < nb) ? buckettotal[b] : 0;
        tsum += v[k];
    }
    ts[t] = tsum;
    __syncthreads();
    for (int ofs = 1; ofs < 256; ofs <<= 1) {
        int val = (t >= ofs) ? ts[t - ofs] : 0;
        __syncthreads();
        ts[t] += val;
        __syncthreads();
    }
    int run = ts[t] - tsum;
#pragma unroll
    for (int k = 0; k < 4; ++k) {
        int b = t * 4 + k;
        if (b < nb) bucketbase[b] = run;
        run += v[k];
    }
    if (t == 0) bucketbase[nb] = E;
}

// ------- pass C: radix-partition scatter with COALESCED writes -------
// Block-local counting sort by bucket in LDS, then packed[delta[i]+i]=vals[i]
// for consecutive i — consecutive lanes hit consecutive addresses within
// each ~5-edge bucket run (vs 64 scattered lines per wave in R6).
__global__ __launch_bounds__(256) void bscatter_kernel(const int* __restrict__ src,
                                                       const int* __restrict__ dst,
                                                       const int* __restrict__ colbase,
                                                       const int* __restrict__ bucketbase,
                                                       int* __restrict__ packed,
                                                       int E, int nb) {
    __shared__ int lofs[NBMAX];   // local hist -> exclusive offsets -> delta
    __shared__ int lcur[NBMAX];   // claim cursors
    __shared__ int vals[CH];
    __shared__ int dlt[CH];       // per-slot (global_base - local_offset)
    int t = threadIdx.x;
    for (int b = t; b < nb; b += 256) lofs[b] = 0;
    __syncthreads();

    int base = blockIdx.x * CH;
    int n = min(CH, E - base);

    int4 dreg[CH / 1024], sreg[CH / 1024];
#pragma unroll
    for (int j = 0; j < CH / 1024; ++j) {
        int idx = base + j * 1024 + t * 4;
        if (idx + 4 <= E) {
            dreg[j] = *(const int4*)(dst + idx);
            sreg[j] = *(const int4*)(src + idx);
            atomicAdd(&lofs[dreg[j].x >> BSHIFT], 1);
            atomicAdd(&lofs[dreg[j].y >> BSHIFT], 1);
            atomicAdd(&lofs[dreg[j].z >> BSHIFT], 1);
            atomicAdd(&lofs[dreg[j].w >> BSHIFT], 1);
        } else {
            int* dp = (int*)&dreg[j];
            int* sp = (int*)&sreg[j];
            for (int k = 0; k < 4; ++k) {
                dp[k] = -1;
                if (idx + k < E) {
                    dp[k] = dst[idx + k];
                    sp[k] = src[idx + k];
                    atomicAdd(&lofs[dp[k] >> BSHIFT], 1);
                }
            }
        }
    }
    __syncthreads();

    // exclusive scan of lofs[0..nb) (thread t handles 4 elements)
    {
        __shared__ int ts[256];
        int v[4];
        int tsum = 0;
#pragma unroll
        for (int k = 0; k < 4; ++k) {
            int b = t * 4 + k;
            v[k] = (b < nb) ? lofs[b] : 0;
            tsum += v[k];
        }
        ts[t] = tsum;
        __syncthreads();
        for (int ofs = 1; ofs < 256; ofs <<= 1) {
            int val = (t >= ofs) ? ts[t - ofs] : 0;
            __syncthreads();
            ts[t] += val;
            __syncthreads();
        }
        int run = ts[t] - tsum;
#pragma unroll
        for (int k = 0; k < 4; ++k) {
            int b = t * 4 + k;
            if (b < nb) {
                lcur[b] = run;  // local exclusive offset (claim cursor)
                // delta = global destination base - local offset
                lofs[b] = bucketbase[b] + colbase[blockIdx.x * nb + b] - run;
            }
            run += v[k];
        }
    }
    __syncthreads();

    // place into LDS (local scatter), recording per-slot dest delta
#pragma unroll
    for (int j = 0; j < CH / 1024; ++j) {
        int* dp = (int*)&dreg[j];
        int* sp = (int*)&sreg[j];
#pragma unroll
        for (int k = 0; k < 4; ++k) {
            int dd = dp[k];
            if (dd >= 0) {
                int b = dd >> BSHIFT;
                int slot = atomicAdd(&lcur[b], 1);
                vals[slot] = ((dd & 127) << 17) | sp[k];
                dlt[slot] = lofs[b];
            }
        }
    }
    __syncthreads();

    // coalesced-run write-out
    for (int i = t; i < n; i += 256) packed[dlt[i] + i] = vals[i];
}

// ---------------- pass D: within-bucket CSR + rowptr + dinv (LDS-cached) ----
__global__ __launch_bounds__(256) void bcsr_kernel(const int* __restrict__ packed,
                                                   const int* __restrict__ bucketbase,
                                                   int* __restrict__ rowptr,
                                                   float* __restrict__ dinv,
                                                   int* __restrict__ csr,
                                                   int N, int nb) {
    __shared__ int deg[128];
    __shared__ int lrp[128];
    __shared__ int ts[128];
    __shared__ int ebuf[MAXB];
    __shared__ int obuf[MAXB];
    int b = blockIdx.x;
    int t = threadIdx.x;
    if (t < 128) deg[t] = 0;
    __syncthreads();
    int bb0 = bucketbase[b];
    int bb1 = bucketbase[b + 1];
    int cnt = bb1 - bb0;
    bool fits = (cnt <= MAXB);
    if (fits) {
        for (int i = t; i < cnt; i += 256) {
            int v = packed[bb0 + i];
            ebuf[i] = v;
            atomicAdd(&deg[v >> 17], 1);
        }
    } else {
        for (int i = t; i < cnt; i += 256)
            atomicAdd(&deg[packed[bb0 + i] >> 17], 1);
    }
    __syncthreads();
    if (t < 128) ts[t] = deg[t];
    __syncthreads();
    for (int ofs = 1; ofs < 128; ofs <<= 1) {
        int v = (t < 128 && t >= ofs) ? ts[t - ofs] : 0;
        __syncthreads();
        if (t < 128) ts[t] += v;
        __syncthreads();
    }
    int node0 = b << BSHIFT;
    int nlocal = min(128, N - node0);
    if (t < 128) lrp[t] = ts[t] - deg[t];
    if (t < nlocal) {
        rowptr[node0 + t] = bb0 + (ts[t] - deg[t]);
        dinv[node0 + t] = rsqrtf((float)(deg[t] + 1));
    }
    if (t == nlocal) rowptr[node0 + nlocal] = bb1;
    __syncthreads();
    if (fits) {
        for (int i = t; i < cnt; i += 256) {
            int v = ebuf[i];
            int p = atomicAdd(&lrp[v >> 17], 1);
            obuf[p] = v & 0x1FFFF;
        }
        __syncthreads();
        for (int i = t; i < cnt; i += 256) csr[bb0 + i] = obuf[i];  // coalesced
    } else {
        for (int i = t; i < cnt; i += 256) {
            int v = packed[bb0 + i];
            int p = atomicAdd(&lrp[v >> 17], 1);
            csr[bb0 + p] = v & 0x1FFFF;
        }
    }
}

// ------- MFMA GEMM: Ybf[M,64](bf16) = (X[M,K] @ W[K,64]) * dinv[row] -------
template <int K, bool XBF16>
__global__ __launch_bounds__(256) void gemm_mfma(const void* __restrict__ Xv,
                                                 const unsigned short* __restrict__ Wt,
                                                 const float* __restrict__ dinv,
                                                 unsigned short* __restrict__ Ybf, int M) {
    constexpr int KP = K + 8;
    __shared__ unsigned short Xs[64 * KP];   // reused as Cs (64*72) in epilogue
    __shared__ unsigned short Ws[64 * KP];
    int t = threadIdx.x;
    int row0 = blockIdx.x * 64;

    for (int i = t; i < 64 * K / 8; i += 256) {
        int r = i / (K / 8), c8 = i % (K / 8);
        *(uint4*)(&Ws[r * KP + c8 * 8]) = ((const uint4*)Wt)[i];
    }
    if (XBF16) {
        const unsigned short* X = (const unsigned short*)Xv;
        for (int i = t; i < 64 * K / 8; i += 256) {
            int r = i / (K / 8), c8 = i % (K / 8);
            int gr = row0 + r;
            uint4 v = make_uint4(0u, 0u, 0u, 0u);
            if (gr < M) v = ((const uint4*)(X + (size_t)gr * K))[c8];
            *(uint4*)(&Xs[r * KP + c8 * 8]) = v;
        }
    } else {
        const float* X = (const float*)Xv;
        for (int i = t; i < 64 * K / 4; i += 256) {
            int r = i / (K / 4), c4 = i % (K / 4);
            int gr = row0 + r;
            float4 v = make_float4(0.f, 0.f, 0.f, 0.f);
            if (gr < M) v = ((const float4*)(X + (size_t)gr * K))[c4];
            uint2 p;
            p.x = pack2(v.x, v.y);
            p.y = pack2(v.z, v.w);
            *(uint2*)(&Xs[r * KP + c4 * 4]) = p;
        }
    }
    __syncthreads();

    int lane = t & 63;
    int w = t >> 6;
    int m = lane & 15;
    int q = lane >> 4;

    f32x4 acc[4];
#pragma unroll
    for (int nt = 0; nt < 4; ++nt) acc[nt] = (f32x4){0.f, 0.f, 0.f, 0.f};

#pragma unroll
    for (int s = 0; s < K / 32; ++s) {
        bf16x8 a = *(const bf16x8*)(&Xs[(16 * w + m) * KP + s * 32 + q * 8]);
#pragma unroll
        for (int nt = 0; nt < 4; ++nt) {
            bf16x8 b = *(const bf16x8*)(&Ws[(16 * nt + m) * KP + s * 32 + q * 8]);
            acc[nt] = __builtin_amdgcn_mfma_f32_16x16x32_bf16(a, b, acc[nt], 0, 0, 0);
        }
    }
    __syncthreads();

    unsigned short* Cs = Xs;
#pragma unroll
    for (int nt = 0; nt < 4; ++nt)
#pragma unroll
        for (int r = 0; r < 4; ++r) {
            int row = 16 * w + q * 4 + r;
            int gr = row0 + row;
            float d = (gr < M) ? dinv[gr] : 0.f;
            Cs[row * 72 + nt * 16 + m] = f2bf(acc[nt][r] * d);
        }
    __syncthreads();
    for (int i = t; i < 64 * 64 / 8; i += 256) {
        int r = i >> 3, c8 = i & 7;
        int gr = row0 + r;
        if (gr < M)
            *(uint4*)(Ybf + (size_t)gr * 64 + c8 * 8) = *(const uint4*)(&Cs[r * 72 + c8 * 8]);
    }
}

// ---------------- pull aggregation + epilogue ----------------
// 8 lanes/node, uint4 (8 bf16) per lane; 16-edge index batches (two coalesced
// int loads) -> 16 independent 128B gathers in flight per batch.
__global__ __launch_bounds__(256) void aggregate_kernel(const unsigned* __restrict__ hsu,
                                                        const int* __restrict__ rowptr,
                                                        const int* __restrict__ csr,
                                                        const float* __restrict__ dinv,
                                                        const float* __restrict__ bias,
                                                        void* __restrict__ outv, int N,
                                                        int do_relu, int obf) {
    int t = threadIdx.x;
    int node = blockIdx.x * 32 + (t >> 3);
    if (node >= N) return;
    int sub = t & 7;
    int gbase = t & 56;

    float acc[8];
    {
        uint4 v = *(const uint4*)(hsu + (size_t)node * 32 + sub * 4);  // self-loop
        acc[0] = blo(v.x); acc[1] = bhi(v.x);
        acc[2] = blo(v.y); acc[3] = bhi(v.y);
        acc[4] = blo(v.z); acc[5] = bhi(v.z);
        acc[6] = blo(v.w); acc[7] = bhi(v.w);
    }
    int e0 = rowptr[node];
    int e1 = rowptr[node + 1];

    int e = e0;
    for (; e + 16 <= e1; e += 16) {
        int idxA = csr[e + sub];
        int idxB = csr[e + 8 + sub];
#pragma unroll
        for (int j = 0; j < 16; ++j) {
            int s = __shfl((j < 8) ? idxA : idxB, gbase + (j & 7), 64);
            uint4 v = *(const uint4*)(hsu + (size_t)s * 32 + sub * 4);
            acc[0] += blo(v.x); acc[1] += bhi(v.x);
            acc[2] += blo(v.y); acc[3] += bhi(v.y);
            acc[4] += blo(v.z); acc[5] += bhi(v.z);
            acc[6] += blo(v.w); acc[7] += bhi(v.w);
        }
    }
    for (; e + 8 <= e1; e += 8) {
        int idx = csr[e + sub];
#pragma unroll
        for (int j = 0; j < 8; ++j) {
            int s = __shfl(idx, gbase + j, 64);
            uint4 v = *(const uint4*)(hsu + (size_t)s * 32 + sub * 4);
            acc[0] += blo(v.x); acc[1] += bhi(v.x);
            acc[2] += blo(v.y); acc[3] += bhi(v.y);
            acc[4] += blo(v.z); acc[5] += bhi(v.z);
            acc[6] += blo(v.w); acc[7] += bhi(v.w);
        }
    }
    for (; e < e1; ++e) {
        int s = csr[e];
        uint4 v = *(const uint4*)(hsu + (size_t)s * 32 + sub * 4);
        acc[0] += blo(v.x); acc[1] += bhi(v.x);
        acc[2] += blo(v.y); acc[3] += bhi(v.y);
        acc[4] += blo(v.z); acc[5] += bhi(v.z);
        acc[6] += blo(v.w); acc[7] += bhi(v.w);
    }

    float d = dinv[node];
    float4 b0 = *(const float4*)(bias + sub * 8);
    float4 b1 = *(const float4*)(bias + sub * 8 + 4);
    float o[8];
    o[0] = fmaf(acc[0], d, b0.x); o[1] = fmaf(acc[1], d, b0.y);
    o[2] = fmaf(acc[2], d, b0.z); o[3] = fmaf(acc[3], d, b0.w);
    o[4] = fmaf(acc[4], d, b1.x); o[5] = fmaf(acc[5], d, b1.y);
    o[6] = fmaf(acc[6], d, b1.z); o[7] = fmaf(acc[7], d, b1.w);
    if (do_relu) {
#pragma unroll
        for (int k = 0; k < 8; ++k) o[k] = fmaxf(o[k], 0.f);
    }
    if (obf) {
        unsigned short* outb = (unsigned short*)outv;
        uint4 p;
        p.x = pack2(o[0], o[1]); p.y = pack2(o[2], o[3]);
        p.z = pack2(o[4], o[5]); p.w = pack2(o[6], o[7]);
        *(uint4*)(outb + (size_t)node * 64 + sub * 8) = p;
    } else {
        float* op = (float*)outv + (size_t)node * 64 + sub * 8;
        *(float4*)(op)     = make_float4(o[0], o[1], o[2], o[3]);
        *(float4*)(op + 4) = make_float4(o[4], o[5], o[6], o[7]);
    }
}

// ---------------- launch ----------------
extern "C" void kernel_launch(void* const* d_in, const int* in_sizes, int n_in,
                              void* d_out, int out_size, void* d_ws, size_t ws_size,
                              hipStream_t stream) {
    const float* x  = (const float*)d_in[0];
    const int*   ei = (const int*)d_in[1];   // [2, E] int32
    const float* W1 = (const float*)d_in[2];
    const float* b1 = (const float*)d_in[3];
    const float* W2 = (const float*)d_in[4];
    const float* b2 = (const float*)d_in[5];

    const int N = in_sizes[0] / 128;  // 100000
    const int E = in_sizes[1] / 2;    // 3200000
    const int* src = ei;
    const int* dst = ei + E;
    float* out = (float*)d_out;

    const int nb   = (N + 127) >> BSHIFT;  // 782
    const int nblk = (E + CH - 1) / CH;    // 782

    char* ws = (char*)d_ws;
    size_t off = 0;
    auto alloc = [&](size_t bytes) -> char* {
        char* p = ws + off;
        off = (off + bytes + 255) & ~(size_t)255;
        return p;
    };
    // persistent
    int*   csr         = (int*)alloc((size_t)E * 4);
    int*   rowptr      = (int*)alloc((size_t)(N + 1) * 4);
    float* dinv        = (float*)alloc((size_t)N * 4);
    int*   bucketbase  = (int*)alloc((size_t)(nb + 1) * 4);
    int*   buckettotal = (int*)alloc((size_t)nb * 4);
    unsigned short* W1t = (unsigned short*)alloc(64 * 128 * 2);
    unsigned short* W2t = (unsigned short*)alloc(64 * 64 * 2);
    unsigned short* bufA = (unsigned short*)alloc((size_t)N * 64 * 2);  // bf16 h*dinv
    unsigned short* bufB = (unsigned short*)alloc((size_t)N * 64 * 2);  // bf16 relu(agg1)
    // transient (dead before gemm1 writes bufA) — alias bufA+bufB region
    int* histmat = (int*)bufA;
    int* packed  = (int*)((char*)bufA + ((size_t)nblk * nb * 4 + 255 & ~(size_t)255) + 256);

    hist_kernel<<<nblk + 48, 256, 0, stream>>>(dst, histmat, E, nb, nblk, W1, W2, W1t, W2t);
    scancol_kernel<<<nb, 256, 0, stream>>>(histmat, histmat, buckettotal, nb, nblk);
    scanbucket_kernel<<<1, 256, 0, stream>>>(buckettotal, bucketbase, nb, E);
    bscatter_kernel<<<nblk, 256, 0, stream>>>(src, dst, histmat, bucketbase, packed, E, nb);
    bcsr_kernel<<<nb, 256, 0, stream>>>(packed, bucketbase, rowptr, dinv, csr, N, nb);

    gemm_mfma<128, false><<<(N + 63) / 64, 256, 0, stream>>>(x, W1t, dinv, bufA, N);
    aggregate_kernel<<<(N + 31) / 32, 256, 0, stream>>>((const unsigned*)bufA, rowptr, csr,
                                                        dinv, b1, bufB, N, 1, 1);
    gemm_mfma<64, true><<<(N + 63) / 64, 256, 0, stream>>>(bufB, W2t, dinv, bufA, N);
    aggregate_kernel<<<(N + 31) / 32, 256, 0, stream>>>((const unsigned*)bufA, rowptr, csr,
                                                        dinv, b2, out, N, 0, 0);
}

// Round 8
// 323.814 us; speedup vs baseline: 1.0766x; 1.0766x over previous
//
#include <hip/hip_runtime.h>
#include <cstdint>

// ===================== GCN encoder on MI355X =====================
// out = gcn(relu(gcn(x, W1, b1)), W2, b2)
// gcn(x,W,b)[i] = dinv[i] * ( sum_{e: dst=i} (xW*dinv)[src] + (xW*dinv)[i] ) + b
// dinv = rsqrt(indeg+1) (self-loop), identical for both layers.
//
// R8: build slimmed to 4 kernels. ghist (grid-stride LDS histogram, ~200k
// global atomics) -> scanbucket(+wprep folded) -> bscatter (R7 block-local
// counting sort, but runs claimed via ONE global atomicAdd per (block,bucket);
// hist/scancol/histmat deleted) -> bcsr. Aggregate reverted to R6 8-batch
// (R7's 16-batch raised VGPR 48->52, dropped occupancy 42->32%, 59->82 us).

#define BSHIFT 7          // 128 nodes per bucket
#define NBMAX 784         // >= ceil(100000/128) = 782
#define CH 8192           // edges per bscatter block
#define MAXB 6016         // LDS-cached bucket capacity in bcsr

typedef __attribute__((ext_vector_type(8))) short bf16x8;
typedef __attribute__((ext_vector_type(4))) float f32x4;

// ---------------- bf16 helpers ----------------
__device__ inline unsigned short f2bf(float f) {
    unsigned u = __float_as_uint(f);
    unsigned r = (u + 0x7FFFu + ((u >> 16) & 1u)) >> 16;  // RNE
    return (unsigned short)r;
}
__device__ inline unsigned pack2(float a, float b) {
    return (unsigned)f2bf(a) | ((unsigned)f2bf(b) << 16);
}
__device__ inline float blo(unsigned u) { return __uint_as_float(u << 16); }
__device__ inline float bhi(unsigned u) { return __uint_as_float(u & 0xFFFF0000u); }

// ---------------- ghist: global bucket histogram ----------------
// 256 blocks, grid-stride; per-block LDS hist, then <=784 global atomics/block.
__global__ __launch_bounds__(256) void ghist_kernel(const int* __restrict__ dst,
                                                    int* __restrict__ bucketcount,
                                                    int E, int nb) {
    __shared__ int hist[NBMAX];
    int t = threadIdx.x;
    for (int b = t; b < nb; b += 256) hist[b] = 0;
    __syncthreads();
    int stride = gridDim.x * 1024;
    for (int idx = blockIdx.x * 1024 + t * 4; idx < E; idx += stride) {
        if (idx + 4 <= E) {
            int4 d = *(const int4*)(dst + idx);
            atomicAdd(&hist[d.x >> BSHIFT], 1);
            atomicAdd(&hist[d.y >> BSHIFT], 1);
            atomicAdd(&hist[d.z >> BSHIFT], 1);
            atomicAdd(&hist[d.w >> BSHIFT], 1);
        } else {
            for (int k = 0; k < 4; ++k)
                if (idx + k < E) atomicAdd(&hist[dst[idx + k] >> BSHIFT], 1);
        }
    }
    __syncthreads();
    for (int b = t; b < nb; b += 256) {
        int h = hist[b];
        if (h) atomicAdd(&bucketcount[b], h);
    }
}

// ------- scanbucket: block 0 scans bucket totals; blocks 1.. do wprep -------
__global__ __launch_bounds__(256) void scanbucket_kernel(const int* __restrict__ bucketcount,
                                                         int* __restrict__ bucketbase,
                                                         int* __restrict__ buckcur,
                                                         int nb, int E,
                                                         const float* __restrict__ W1,
                                                         const float* __restrict__ W2,
                                                         unsigned short* __restrict__ W1t,
                                                         unsigned short* __restrict__ W2t) {
    if (blockIdx.x > 0) {
        // weight prep: W[K][64] fp32 -> Wt[64][K] bf16
        int i = (blockIdx.x - 1) * 256 + threadIdx.x;
        if (i < 128 * 64) {
            int k = i >> 6, n = i & 63;
            W1t[n * 128 + k] = f2bf(W1[i]);
        }
        int j = i - 128 * 64;
        if (j >= 0 && j < 64 * 64) {
            int k = j >> 6, n = j & 63;
            W2t[n * 64 + k] = f2bf(W2[j]);
        }
        return;
    }
    __shared__ int ts[256];
    int t = threadIdx.x;
    int v[4];
    int tsum = 0;
#pragma unroll
    for (int k = 0; k < 4; ++k) {
        int b = t * 4 + k;
        v[k] = (b < nb) ? bucketcount[b] : 0;
        tsum += v[k];
    }
    ts[t] = tsum;
    __syncthreads();
    for (int ofs = 1; ofs < 256; ofs <<= 1) {
        int val = (t >= ofs) ? ts[t - ofs] : 0;
        __syncthreads();
        ts[t] += val;
        __syncthreads();
    }
    int run = ts[t] - tsum;
#pragma unroll
    for (int k = 0; k < 4; ++k) {
        int b = t * 4 + k;
        if (b < nb) {
            bucketbase[b] = run;
            buckcur[b] = run;
        }
        run += v[k];
    }
    if (t == 0) bucketbase[nb] = E;
}

// ------- bscatter: block-local counting sort + atomic run claims -------
// Pass1: LDS hist of this block's CH edges. Scan -> local offsets; claim a
// contiguous global run per bucket via one atomicAdd(&buckcur[b], cnt).
// Pass2: re-read edges (L2-hot), place into LDS in bucket order with per-slot
// dest delta. Write-out fully coalesced: packed[dlt[i]+i] = vals[i].
__global__ __launch_bounds__(256) void bscatter_kernel(const int* __restrict__ src,
                                                       const int* __restrict__ dst,
                                                       int* __restrict__ buckcur,
                                                       int* __restrict__ packed,
                                                       int E, int nb) {
    __shared__ int lofs[NBMAX];   // hist -> (global_run_base - local_offset)
    __shared__ int lcur[NBMAX];   // local claim cursors
    __shared__ int vals[CH];
    __shared__ int dlt[CH];
    __shared__ int ts[256];
    int t = threadIdx.x;
    for (int b = t; b < nb; b += 256) lofs[b] = 0;
    __syncthreads();

    int base = blockIdx.x * CH;
    int n = min(CH, E - base);

#pragma unroll
    for (int j = 0; j < CH / 1024; ++j) {
        int idx = base + j * 1024 + t * 4;
        if (idx + 4 <= E) {
            int4 d = *(const int4*)(dst + idx);
            atomicAdd(&lofs[d.x >> BSHIFT], 1);
            atomicAdd(&lofs[d.y >> BSHIFT], 1);
            atomicAdd(&lofs[d.z >> BSHIFT], 1);
            atomicAdd(&lofs[d.w >> BSHIFT], 1);
        } else {
            for (int k = 0; k < 4; ++k)
                if (idx + k < E) atomicAdd(&lofs[dst[idx + k] >> BSHIFT], 1);
        }
    }
    __syncthreads();

    // exclusive scan of local hist; claim global runs
    {
        int v[4];
        int tsum = 0;
#pragma unroll
        for (int k = 0; k < 4; ++k) {
            int b = t * 4 + k;
            v[k] = (b < nb) ? lofs[b] : 0;
            tsum += v[k];
        }
        ts[t] = tsum;
        __syncthreads();
        for (int ofs = 1; ofs < 256; ofs <<= 1) {
            int val = (t >= ofs) ? ts[t - ofs] : 0;
            __syncthreads();
            ts[t] += val;
            __syncthreads();
        }
        int run = ts[t] - tsum;
#pragma unroll
        for (int k = 0; k < 4; ++k) {
            int b = t * 4 + k;
            if (b < nb) {
                lcur[b] = run;
                int g = v[k] ? atomicAdd(&buckcur[b], v[k]) : 0;
                lofs[b] = g - run;   // dest delta for this bucket
            }
            run += v[k];
        }
    }
    __syncthreads();

    // pass2: re-read and place locally
#pragma unroll
    for (int j = 0; j < CH / 1024; ++j) {
        int idx = base + j * 1024 + t * 4;
        if (idx + 4 <= E) {
            int4 d = *(const int4*)(dst + idx);
            int4 s = *(const int4*)(src + idx);
            int b, slot;
            b = d.x >> BSHIFT; slot = atomicAdd(&lcur[b], 1);
            vals[slot] = ((d.x & 127) << 17) | s.x; dlt[slot] = lofs[b];
            b = d.y >> BSHIFT; slot = atomicAdd(&lcur[b], 1);
            vals[slot] = ((d.y & 127) << 17) | s.y; dlt[slot] = lofs[b];
            b = d.z >> BSHIFT; slot = atomicAdd(&lcur[b], 1);
            vals[slot] = ((d.z & 127) << 17) | s.z; dlt[slot] = lofs[b];
            b = d.w >> BSHIFT; slot = atomicAdd(&lcur[b], 1);
            vals[slot] = ((d.w & 127) << 17) | s.w; dlt[slot] = lofs[b];
        } else {
            for (int k = 0; k < 4; ++k)
                if (idx + k < E) {
                    int dd = dst[idx + k], ss = src[idx + k];
                    int b = dd >> BSHIFT;
                    int slot = atomicAdd(&lcur[b], 1);
                    vals[slot] = ((dd & 127) << 17) | ss;
                    dlt[slot] = lofs[b];
                }
        }
    }
    __syncthreads();

    for (int i = t; i < n; i += 256) packed[dlt[i] + i] = vals[i];  // coalesced runs
}

// ---------------- bcsr: within-bucket CSR + rowptr + dinv (LDS-cached) ------
__global__ __launch_bounds__(256) void bcsr_kernel(const int* __restrict__ packed,
                                                   const int* __restrict__ bucketbase,
                                                   int* __restrict__ rowptr,
                                                   float* __restrict__ dinv,
                                                   int* __restrict__ csr,
                                                   int N, int nb) {
    __shared__ int deg[128];
    __shared__ int lrp[128];
    __shared__ int ts[128];
    __shared__ int ebuf[MAXB];
    __shared__ int obuf[MAXB];
    int b = blockIdx.x;
    int t = threadIdx.x;
    if (t < 128) deg[t] = 0;
    __syncthreads();
    int bb0 = bucketbase[b];
    int bb1 = bucketbase[b + 1];
    int cnt = bb1 - bb0;
    bool fits = (cnt <= MAXB);
    if (fits) {
        for (int i = t; i < cnt; i += 256) {
            int v = packed[bb0 + i];
            ebuf[i] = v;
            atomicAdd(&deg[v >> 17], 1);
        }
    } else {
        for (int i = t; i < cnt; i += 256)
            atomicAdd(&deg[packed[bb0 + i] >> 17], 1);
    }
    __syncthreads();
    if (t < 128) ts[t] = deg[t];
    __syncthreads();
    for (int ofs = 1; ofs < 128; ofs <<= 1) {
        int v = (t < 128 && t >= ofs) ? ts[t - ofs] : 0;
        __syncthreads();
        if (t < 128) ts[t] += v;
        __syncthreads();
    }
    int node0 = b << BSHIFT;
    int nlocal = min(128, N - node0);
    if (t < 128) lrp[t] = ts[t] - deg[t];
    if (t < nlocal) {
        rowptr[node0 + t] = bb0 + (ts[t] - deg[t]);
        dinv[node0 + t] = rsqrtf((float)(deg[t] + 1));
    }
    if (t == nlocal) rowptr[node0 + nlocal] = bb1;
    __syncthreads();
    if (fits) {
        for (int i = t; i < cnt; i += 256) {
            int v = ebuf[i];
            int p = atomicAdd(&lrp[v >> 17], 1);
            obuf[p] = v & 0x1FFFF;
        }
        __syncthreads();
        for (int i = t; i < cnt; i += 256) csr[bb0 + i] = obuf[i];  // coalesced
    } else {
        for (int i = t; i < cnt; i += 256) {
            int v = packed[bb0 + i];
            int p = atomicAdd(&lrp[v >> 17], 1);
            csr[bb0 + p] = v & 0x1FFFF;
        }
    }
}

// ------- MFMA GEMM: Ybf[M,64](bf16) = (X[M,K] @ W[K,64]) * dinv[row] -------
template <int K, bool XBF16>
__global__ __launch_bounds__(256) void gemm_mfma(const void* __restrict__ Xv,
                                                 const unsigned short* __restrict__ Wt,
                                                 const float* __restrict__ dinv,
                                                 unsigned short* __restrict__ Ybf, int M) {
    constexpr int KP = K + 8;
    __shared__ unsigned short Xs[64 * KP];   // reused as Cs (64*72) in epilogue
    __shared__ unsigned short Ws[64 * KP];
    int t = threadIdx.x;
    int row0 = blockIdx.x * 64;

    for (int i = t; i < 64 * K / 8; i += 256) {
        int r = i / (K / 8), c8 = i % (K / 8);
        *(uint4*)(&Ws[r * KP + c8 * 8]) = ((const uint4*)Wt)[i];
    }
    if (XBF16) {
        const unsigned short* X = (const unsigned short*)Xv;
        for (int i = t; i < 64 * K / 8; i += 256) {
            int r = i / (K / 8), c8 = i % (K / 8);
            int gr = row0 + r;
            uint4 v = make_uint4(0u, 0u, 0u, 0u);
            if (gr < M) v = ((const uint4*)(X + (size_t)gr * K))[c8];
            *(uint4*)(&Xs[r * KP + c8 * 8]) = v;
        }
    } else {
        const float* X = (const float*)Xv;
        for (int i = t; i < 64 * K / 4; i += 256) {
            int r = i / (K / 4), c4 = i % (K / 4);
            int gr = row0 + r;
            float4 v = make_float4(0.f, 0.f, 0.f, 0.f);
            if (gr < M) v = ((const float4*)(X + (size_t)gr * K))[c4];
            uint2 p;
            p.x = pack2(v.x, v.y);
            p.y = pack2(v.z, v.w);
            *(uint2*)(&Xs[r * KP + c4 * 4]) = p;
        }
    }
    __syncthreads();

    int lane = t & 63;
    int w = t >> 6;
    int m = lane & 15;
    int q = lane >> 4;

    f32x4 acc[4];
#pragma unroll
    for (int nt = 0; nt < 4; ++nt) acc[nt] = (f32x4){0.f, 0.f, 0.f, 0.f};

#pragma unroll
    for (int s = 0; s < K / 32; ++s) {
        bf16x8 a = *(const bf16x8*)(&Xs[(16 * w + m) * KP + s * 32 + q * 8]);
#pragma unroll
        for (int nt = 0; nt < 4; ++nt) {
            bf16x8 b = *(const bf16x8*)(&Ws[(16 * nt + m) * KP + s * 32 + q * 8]);
            acc[nt] = __builtin_amdgcn_mfma_f32_16x16x32_bf16(a, b, acc[nt], 0, 0, 0);
        }
    }
    __syncthreads();

    unsigned short* Cs = Xs;
#pragma unroll
    for (int nt = 0; nt < 4; ++nt)
#pragma unroll
        for (int r = 0; r < 4; ++r) {
            int row = 16 * w + q * 4 + r;
            int gr = row0 + row;
            float d = (gr < M) ? dinv[gr] : 0.f;
            Cs[row * 72 + nt * 16 + m] = f2bf(acc[nt][r] * d);
        }
    __syncthreads();
    for (int i = t; i < 64 * 64 / 8; i += 256) {
        int r = i >> 3, c8 = i & 7;
        int gr = row0 + r;
        if (gr < M)
            *(uint4*)(Ybf + (size_t)gr * 64 + c8 * 8) = *(const uint4*)(&Cs[r * 72 + c8 * 8]);
    }
}

// ---------------- pull aggregation + epilogue (R6 version) ----------------
__global__ __launch_bounds__(256) void aggregate_kernel(const unsigned* __restrict__ hsu,
                                                        const int* __restrict__ rowptr,
                                                        const int* __restrict__ csr,
                                                        const float* __restrict__ dinv,
                                                        const float* __restrict__ bias,
                                                        void* __restrict__ outv, int N,
                                                        int do_relu, int obf) {
    int t = threadIdx.x;
    int node = blockIdx.x * 32 + (t >> 3);
    if (node >= N) return;
    int sub = t & 7;
    int gbase = t & 56;

    float acc[8];
    {
        uint4 v = *(const uint4*)(hsu + (size_t)node * 32 + sub * 4);  // self-loop
        acc[0] = blo(v.x); acc[1] = bhi(v.x);
        acc[2] = blo(v.y); acc[3] = bhi(v.y);
        acc[4] = blo(v.z); acc[5] = bhi(v.z);
        acc[6] = blo(v.w); acc[7] = bhi(v.w);
    }
    int e0 = rowptr[node];
    int e1 = rowptr[node + 1];

    int e = e0;
    for (; e + 8 <= e1; e += 8) {
        int idx = csr[e + sub];
#pragma unroll
        for (int j = 0; j < 8; ++j) {
            int s = __shfl(idx, gbase + j, 64);
            uint4 v = *(const uint4*)(hsu + (size_t)s * 32 + sub * 4);
            acc[0] += blo(v.x); acc[1] += bhi(v.x);
            acc[2] += blo(v.y); acc[3] += bhi(v.y);
            acc[4] += blo(v.z); acc[5] += bhi(v.z);
            acc[6] += blo(v.w); acc[7] += bhi(v.w);
        }
    }
    for (; e < e1; ++e) {
        int s = csr[e];
        uint4 v = *(const uint4*)(hsu + (size_t)s * 32 + sub * 4);
        acc[0] += blo(v.x); acc[1] += bhi(v.x);
        acc[2] += blo(v.y); acc[3] += bhi(v.y);
        acc[4] += blo(v.z); acc[5] += bhi(v.z);
        acc[6] += blo(v.w); acc[7] += bhi(v.w);
    }

    float d = dinv[node];
    float4 b0 = *(const float4*)(bias + sub * 8);
    float4 b1 = *(const float4*)(bias + sub * 8 + 4);
    float o[8];
    o[0] = fmaf(acc[0], d, b0.x); o[1] = fmaf(acc[1], d, b0.y);
    o[2] = fmaf(acc[2], d, b0.z); o[3] = fmaf(acc[3], d, b0.w);
    o[4] = fmaf(acc[4], d, b1.x); o[5] = fmaf(acc[5], d, b1.y);
    o[6] = fmaf(acc[6], d, b1.z); o[7] = fmaf(acc[7], d, b1.w);
    if (do_relu) {
#pragma unroll
        for (int k = 0; k < 8; ++k) o[k] = fmaxf(o[k], 0.f);
    }
    if (obf) {
        unsigned short* outb = (unsigned short*)outv;
        uint4 p;
        p.x = pack2(o[0], o[1]); p.y = pack2(o[2], o[3]);
        p.z = pack2(o[4], o[5]); p.w = pack2(o[6], o[7]);
        *(uint4*)(outb + (size_t)node * 64 + sub * 8) = p;
    } else {
        float* op = (float*)outv + (size_t)node * 64 + sub * 8;
        *(float4*)(op)     = make_float4(o[0], o[1], o[2], o[3]);
        *(float4*)(op + 4) = make_float4(o[4], o[5], o[6], o[7]);
    }
}

// ---------------- launch ----------------
extern "C" void kernel_launch(void* const* d_in, const int* in_sizes, int n_in,
                              void* d_out, int out_size, void* d_ws, size_t ws_size,
                              hipStream_t stream) {
    const float* x  = (const float*)d_in[0];
    const int*   ei = (const int*)d_in[1];   // [2, E] int32
    const float* W1 = (const float*)d_in[2];
    const float* b1 = (const float*)d_in[3];
    const float* W2 = (const float*)d_in[4];
    const float* b2 = (const float*)d_in[5];

    const int N = in_sizes[0] / 128;  // 100000
    const int E = in_sizes[1] / 2;    // 3200000
    const int* src = ei;
    const int* dst = ei + E;
    float* out = (float*)d_out;

    const int nb    = (N + 127) >> BSHIFT;  // 782
    const int nblk  = (E + CH - 1) / CH;    // 391

    char* ws = (char*)d_ws;
    size_t off = 0;
    auto alloc = [&](size_t bytes) -> char* {
        char* p = ws + off;
        off = (off + bytes + 255) & ~(size_t)255;
        return p;
    };
    // persistent
    int*   csr         = (int*)alloc((size_t)E * 4);
    int*   rowptr      = (int*)alloc((size_t)(N + 1) * 4);
    float* dinv        = (float*)alloc((size_t)N * 4);
    int*   bucketbase  = (int*)alloc((size_t)(nb + 1) * 4);
    int*   bucketcount = (int*)alloc((size_t)nb * 4);
    int*   buckcur     = (int*)alloc((size_t)nb * 4);
    unsigned short* W1t = (unsigned short*)alloc(64 * 128 * 2);
    unsigned short* W2t = (unsigned short*)alloc(64 * 64 * 2);
    unsigned short* bufA = (unsigned short*)alloc((size_t)N * 64 * 2);  // bf16 h*dinv
    unsigned short* bufB = (unsigned short*)alloc((size_t)N * 64 * 2);  // bf16 relu(agg1)
    // transient: packed (E*4 = 12.8 MB) aliases bufA (12.8 MB) — dead before gemm1
    int* packed = (int*)bufA;

    hipMemsetAsync(bucketcount, 0, (size_t)nb * 4, stream);
    ghist_kernel<<<256, 256, 0, stream>>>(dst, bucketcount, E, nb);
    scanbucket_kernel<<<49, 256, 0, stream>>>(bucketcount, bucketbase, buckcur, nb, E,
                                              W1, W2, W1t, W2t);
    bscatter_kernel<<<nblk, 256, 0, stream>>>(src, dst, buckcur, packed, E, nb);
    bcsr_kernel<<<nb, 256, 0, stream>>>(packed, bucketbase, rowptr, dinv, csr, N, nb);

    gemm_mfma<128, false><<<(N + 63) / 64, 256, 0, stream>>>(x, W1t, dinv, bufA, N);
    aggregate_kernel<<<(N + 31) / 32, 256, 0, stream>>>((const unsigned*)bufA, rowptr, csr,
                                                        dinv, b1, bufB, N, 1, 1);
    gemm_mfma<64, true><<<(N + 63) / 64, 256, 0, stream>>>(bufB, W2t, dinv, bufA, N);
    aggregate_kernel<<<(N + 31) / 32, 256, 0, stream>>>((const unsigned*)bufA, rowptr, csr,
                                                        dinv, b2, out, N, 0, 0);
}